// Round 1
// baseline (838.227 us; speedup 1.0000x reference)
//
#include <hip/hip_runtime.h>

#define BB 256
#define TT 1024
#define II 128
#define HH 64
#define BT (BB * TT)

typedef _Float16 h2 __attribute__((ext_vector_type(2)));
typedef _Float16 half8 __attribute__((ext_vector_type(8)));
typedef float f32x4 __attribute__((ext_vector_type(4)));
typedef unsigned int uint;
typedef unsigned short ushort;

#define DOT2(a, b, c) __builtin_amdgcn_fdot2((a), (b), (c), false)
#define BC(u) __builtin_bit_cast(h2, (uint)(u))
#define MFMA16(a, b, c) __builtin_amdgcn_mfma_f32_16x16x32_f16((a), (b), (c), 0, 0, 0)
#define SIG(v) __builtin_amdgcn_rcpf(1.0f + __expf(-(v)))
#define TNH(v) (1.0f - 2.0f * __builtin_amdgcn_rcpf(1.0f + __expf(2.0f * (v))))

// R10 tail barriers: counted lgkm so prefetch ds_reads stay IN FLIGHT across
// the barrier (DS completes in-order within a wave; lgkmcnt(8) retires the
// single ds_write issued before the 8 readback reads — the write is the only
// cross-wave obligation). Q2 publishes nothing through LDS -> bare barrier.
#define BAR_W8() asm volatile("s_waitcnt lgkmcnt(8)\n\ts_barrier" ::: "memory")
#define BAR_W0() asm volatile("s_waitcnt lgkmcnt(0)\n\ts_barrier" ::: "memory")
#define BAR_NP() asm volatile("s_barrier" ::: "memory")

#define LDPK(P, ptr) uint P; { float2 _f = *(const float2*)(ptr); \
    h2 _h; _h[0] = (_Float16)_f.x; _h[1] = (_Float16)_f.y; \
    P = __builtin_bit_cast(uint, _h); }
#define PIN8(a,b,c,d,e,f,g,h_) asm volatile("" : "+v"(a),"+v"(b),"+v"(c),"+v"(d),"+v"(e),"+v"(f),"+v"(g),"+v"(h_));
#define LD8(P, base, o) \
    LDPK(P##0,(base)+(o)+ 0) LDPK(P##1,(base)+(o)+ 2) LDPK(P##2,(base)+(o)+ 4) LDPK(P##3,(base)+(o)+ 6) \
    LDPK(P##4,(base)+(o)+ 8) LDPK(P##5,(base)+(o)+10) LDPK(P##6,(base)+(o)+12) LDPK(P##7,(base)+(o)+14) \
    PIN8(P##0,P##1,P##2,P##3,P##4,P##5,P##6,P##7)

// 8 packs vs 2 broadcast uint4 (16 vals) into explicit acc chain c0..c3
#define D8A(P, va, vb, c0, c1, c2, c3) \
    c0 = DOT2(BC(P##0), BC((va).x), c0); c1 = DOT2(BC(P##1), BC((va).y), c1); \
    c2 = DOT2(BC(P##2), BC((va).z), c2); c3 = DOT2(BC(P##3), BC((va).w), c3); \
    c0 = DOT2(BC(P##4), BC((vb).x), c0); c1 = DOT2(BC(P##5), BC((vb).y), c1); \
    c2 = DOT2(BC(P##6), BC((vb).z), c2); c3 = DOT2(BC(P##7), BC((vb).w), c3);

// full 64-wide row dot for gate: 4 x D8A over hv0..hv7
#define GDOT(G, s) { float a0=0.f,a1=0.f,a2=0.f,a3=0.f; \
    D8A(G##A, hv0, hv1, a0,a1,a2,a3) D8A(G##B, hv2, hv3, a0,a1,a2,a3) \
    D8A(G##C, hv4, hv5, a0,a1,a2,a3) D8A(G##D, hv6, hv7, a0,a1,a2,a3) \
    s = (a0 + a1) + (a2 + a3); }

// load full h-vector (64 f16 = 8 x b128 broadcast) into hv0..hv7 registers
#define LDHV(src) { const uint4* hq_ = (const uint4*)(src); \
    hv0=hq_[0]; hv1=hq_[1]; hv2=hq_[2]; hv3=hq_[3]; \
    hv4=hq_[4]; hv5=hq_[5]; hv6=hq_[6]; hv7=hq_[7]; }

// ============ Kernel A: xg[bt][4j+g] = x[bt,:] . w_ih0[g*64+j,:]  (f16) ======
// R10: W-rows are PERMUTED at LDS-staging time (srcrow = (flat&3)*64+flat>>2)
// so MFMA output column `flat` already IS the [bt][4j+g] slot -> the epilogue
// stores dense 32B sectors (16 consecutive ushorts per 16-lane group) instead
// of 2B-at-stride-8B scatter (~4x HBM write amplification before).
__global__ __launch_bounds__(256)
void xg_mfma(const float* __restrict__ x, const float* __restrict__ w_ih0,
             ushort* __restrict__ xg)
{
    __shared__ __align__(16) _Float16 xt[64][136];
    __shared__ __align__(16) _Float16 wt[128][136];
    const int tid = threadIdx.x, lane = tid & 63, wv = tid >> 6;
    const int bt0 = blockIdx.x * 64;
    {
        const int row = tid >> 2, q = (tid & 3) * 32;
        const float4* src = (const float4*)(x + (size_t)(bt0 + row) * II + q);
        _Float16* dst = &xt[row][q];
        #pragma unroll
        for (int i = 0; i < 8; ++i) {
            float4 v = src[i];
            dst[4*i+0]=(_Float16)v.x; dst[4*i+1]=(_Float16)v.y;
            dst[4*i+2]=(_Float16)v.z; dst[4*i+3]=(_Float16)v.w;
        }
    }
    for (int nh = 0; nh < 2; ++nh) {
        __syncthreads();
        {
            const int n = tid >> 1, kh = (tid & 1) * 64;
            const int flatn = nh * 128 + n;
            const int srcrow = (flatn & 3) * 64 + (flatn >> 2);   // gate-row permute
            const float4* src = (const float4*)(w_ih0 + (size_t)srcrow * II + kh);
            _Float16* dst = &wt[n][kh];
            #pragma unroll
            for (int i = 0; i < 16; ++i) {
                float4 v = src[i];
                dst[4*i+0]=(_Float16)v.x; dst[4*i+1]=(_Float16)v.y;
                dst[4*i+2]=(_Float16)v.z; dst[4*i+3]=(_Float16)v.w;
            }
        }
        __syncthreads();
        const int m = wv * 16 + (lane & 15);
        const int kf = (lane >> 4) * 8;
        half8 a0 = *(const half8*)&xt[m][ 0 + kf];
        half8 a1 = *(const half8*)&xt[m][32 + kf];
        half8 a2 = *(const half8*)&xt[m][64 + kf];
        half8 a3 = *(const half8*)&xt[m][96 + kf];
        #pragma unroll
        for (int nt = 0; nt < 8; ++nt) {
            const int nloc = nt * 16 + (lane & 15);
            half8 b0 = *(const half8*)&wt[nloc][ 0 + kf];
            half8 b1 = *(const half8*)&wt[nloc][32 + kf];
            half8 b2 = *(const half8*)&wt[nloc][64 + kf];
            half8 b3 = *(const half8*)&wt[nloc][96 + kf];
            f32x4 acc = {0.f, 0.f, 0.f, 0.f};
            acc = MFMA16(a0, b0, acc); acc = MFMA16(a1, b1, acc);
            acc = MFMA16(a2, b2, acc); acc = MFMA16(a3, b3, acc);
            const int colg = nh * 128 + nt * 16 + (lane & 15);  // == [4j+g] slot
            const int r0   = wv * 16 + (lane >> 4) * 4;
            #pragma unroll
            for (int r = 0; r < 4; ++r) {
                _Float16 hv = (_Float16)acc[r];
                xg[(size_t)(bt0 + r0 + r) * 256 + colg] = __builtin_bit_cast(ushort, hv);
            }
        }
    }
}

// ============ Kernel B: 3-wave pipelined recurrence, 1 block per batch elem ==
// Wave 0 (P):  h0(k)   = lstm0(xg(k), h0(k-1))            [W_hh0 in-lane]
// Wave 1 (Q1): z(k-2)  = W_ih1 . h0(k-2)                  [W_ih1 in-lane]
// Wave 2 (Q2): h1(k-4) = act(z(k-4) + W_hh1.h1(k-5) + b)  [W_hh1 in-lane]
// R10 restructure: every wave consumes h-vectors from REGISTERS prefetched one
// full barrier interval earlier; quad-buffered h0/z give >=3-interval reuse
// slack so in-flight reads can straggle across barriers safely. Tail waits are
// counted (see BAR_* comments) so only the cross-wave ds_write is drained at
// the barrier — the post-barrier ds_read latency that dominated the old 1385
// cy/step is gone from the critical path.
__global__ __launch_bounds__(192) __attribute__((amdgpu_waves_per_eu(1, 1)))
void lstm2_core(const float* __restrict__ w_hh0,
                const float* __restrict__ b_ih0, const float* __restrict__ b_hh0,
                const float* __restrict__ w_ih1, const float* __restrict__ w_hh1,
                const float* __restrict__ b_ih1, const float* __restrict__ b_hh1,
                const ushort* __restrict__ xg, ushort* __restrict__ h1g)
{
    const int bb = blockIdx.x;
    const int w  = threadIdx.x >> 6;
    const int j  = threadIdx.x & 63;

    __shared__ __align__(16) uint  h0buf[4][32];     // quad-buffered, 64 f16 each
    __shared__ __align__(16) uint  h1buf[32];        // Q2-private (single buffer)
    __shared__ __align__(16) float zbuf[4][64][4];   // quad-buffered float4/lane

    // ---- weights: all three waves load a [256][64] matrix, 4 rows/lane ----
    const float* Wsel = (w == 0) ? w_hh0 : (w == 1) ? w_ih1 : w_hh1;
    const float* r0p = Wsel + (size_t)(  0 + j) * 64;
    const float* r1p = Wsel + (size_t)( 64 + j) * 64;
    const float* r2p = Wsel + (size_t)(128 + j) * 64;
    const float* r3p = Wsel + (size_t)(192 + j) * 64;
    LD8(G0A, r0p,  0) LD8(G0B, r0p, 16) LD8(G0C, r0p, 32) LD8(G0D, r0p, 48)
    LD8(G1A, r1p,  0) LD8(G1B, r1p, 16) LD8(G1C, r1p, 32) LD8(G1D, r1p, 48)
    LD8(G2A, r2p,  0) LD8(G2B, r2p, 16) LD8(G2C, r2p, 32) LD8(G2D, r2p, 48)
    LD8(G3A, r3p,  0) LD8(G3B, r3p, 16) LD8(G3C, r3p, 32) LD8(G3D, r3p, 48)

    // biases (P: layer0, Q2: layer1, Q1: unused zeros)
    float bI = 0.f, bF = 0.f, bG = 0.f, bO = 0.f;
    if (w == 0) {
        bI = b_ih0[j]       + b_hh0[j];
        bF = b_ih0[64 + j]  + b_hh0[64 + j];
        bG = b_ih0[128 + j] + b_hh0[128 + j];
        bO = b_ih0[192 + j] + b_hh0[192 + j];
    } else if (w == 2) {
        bI = b_ih1[j]       + b_hh1[j];
        bF = b_ih1[64 + j]  + b_hh1[64 + j];
        bG = b_ih1[128 + j] + b_hh1[128 + j];
        bO = b_ih1[192 + j] + b_hh1[192 + j];
    }

    float cst = 0.0f;
    const ushort* xbase = xg + (size_t)bb * TT * 256 + j * 4;
    ushort* h1b = h1g + (size_t)bb * TT * 64 + j;

    // loop-carried register state
    uint4 hv0={0,0,0,0}, hv1={0,0,0,0}, hv2={0,0,0,0}, hv3={0,0,0,0};
    uint4 hv4={0,0,0,0}, hv5={0,0,0,0}, hv6={0,0,0,0}, hv7={0,0,0,0};
    f32x4 zr = {0.f, 0.f, 0.f, 0.f};
    uint2 xc = {0,0}, xn1 = {0,0}, xn2 = {0,0};
    if (w == 0) {
        xc  = *(const uint2*)(xbase);
        xn1 = *(const uint2*)(xbase + 256);
    }

    // No LDS zero-init needed: every LDS read is downstream (>=1 barrier) of
    // its producing write; step -1 states live in the zeroed registers above.
    for (int k = 0; k < TT + 4; ++k) {
        if (w == 0) {
            // ---------------- P: layer-0 step k ----------------
            if (k + 2 < TT) xn2 = *(const uint2*)(xbase + (size_t)(k + 2) * 256);
            if (k < TT) {
                float si, sf, sg, so;                  // hv = h0(k-1), resident
                GDOT(G0, si) GDOT(G1, sf) GDOT(G2, sg) GDOT(G3, so)
                h2 xlo = BC(xc.x), xhi = BC(xc.y);     // [i,f] [g,o]
                si += bI + (float)xlo[0]; sf += bF + (float)xlo[1];
                sg += bG + (float)xhi[0]; so += bO + (float)xhi[1];
                float ii = SIG(si), ff = SIG(sf), gg = TNH(sg), oo = SIG(so);
                cst = fmaf(ff, cst, ii * gg);
                float hval = oo * TNH(cst);
                ((_Float16*)&h0buf[k & 3][0])[j] = (_Float16)hval;  // publish
                LDHV(&h0buf[k & 3][0]);               // self-readback, spans barrier
            }
            xc = xn1; xn1 = xn2;
            BAR_W8();                                  // retire write only
        } else if (w == 1) {
            // ---------------- Q1: z(k-2) = W_ih1 . h0(k-2) ----------------
            if (k >= 2 && k < TT + 2) {
                const int m = k - 2;                   // hv = h0(m), resident
                float si, sf, sg, so;
                GDOT(G0, si) GDOT(G1, sf) GDOT(G2, sg) GDOT(G3, so)
                f32x4 zv = {si, sf, sg, so};
                *(f32x4*)&zbuf[m & 3][j][0] = zv;      // one ds_write_b128
            }
            if (k >= 1 && k <= TT)                     // prefetch h0(k-1) for k+1
                LDHV(&h0buf[(k - 1) & 3][0]);
            BAR_W0();                                  // lightest wave: full drain
        } else {
            // ---------------- Q2: layer-1 step m = k-4 ----------------
            if (k >= 4) {
                const int m = k - 4;                   // hv = h1(m-1), zr = z(m)
                float si, sf, sg, so;
                GDOT(G0, si) GDOT(G1, sf) GDOT(G2, sg) GDOT(G3, so)
                si += bI + zr[0]; sf += bF + zr[1];
                sg += bG + zr[2]; so += bO + zr[3];
                float ii = SIG(si), ff = SIG(sf), gg = TNH(sg), oo = SIG(so);
                cst = fmaf(ff, cst, ii * gg);
                float hval = oo * TNH(cst);
                _Float16 hf = (_Float16)hval;
                ((_Float16*)&h1buf[0])[j] = hf;        // private publish
                LDHV(&h1buf[0]);                       // self-readback
                h1b[(size_t)m * 64] = __builtin_bit_cast(ushort, hf);
            }
            if (k >= 3 && k < TT + 3)                  // prefetch z(k-3) for k+1
                zr = *(const f32x4*)&zbuf[(k - 3) & 3][j][0];
            BAR_NP();                                  // no cross-wave writes
        }
    }
}

// ============ Kernel C: out[bt] = sigmoid(h1g[bt,:] . w_out + b_out) =========
__global__ __launch_bounds__(256)
void head_gemv(const ushort* __restrict__ h1g, const float* __restrict__ w_out,
               const float* __restrict__ b_out, float* __restrict__ outp)
{
    __shared__ float wsh[64];
    const int tid = threadIdx.x;
    if (tid < 64) wsh[tid] = w_out[tid];
    __syncthreads();
    const int bt = blockIdx.x * 256 + tid;
    const uint4* hp = (const uint4*)(h1g + (size_t)bt * 64);
    float s = 0.0f;
    #pragma unroll
    for (int i = 0; i < 8; ++i) {
        uint4 v = hp[i];
        const float* wp = &wsh[8 * i];
        h2 p;
        p = BC(v.x); s = fmaf((float)p[0], wp[0], s); s = fmaf((float)p[1], wp[1], s);
        p = BC(v.y); s = fmaf((float)p[0], wp[2], s); s = fmaf((float)p[1], wp[3], s);
        p = BC(v.z); s = fmaf((float)p[0], wp[4], s); s = fmaf((float)p[1], wp[5], s);
        p = BC(v.w); s = fmaf((float)p[0], wp[6], s); s = fmaf((float)p[1], wp[7], s);
    }
    outp[bt] = __builtin_amdgcn_rcpf(1.0f + __expf(-(s + b_out[0])));
}

extern "C" void kernel_launch(void* const* d_in, const int* in_sizes, int n_in,
                              void* d_out, int out_size, void* d_ws, size_t ws_size,
                              hipStream_t stream) {
    const float* x     = (const float*)d_in[0];
    const float* w_ih0 = (const float*)d_in[1];
    const float* w_hh0 = (const float*)d_in[2];
    const float* b_ih0 = (const float*)d_in[3];
    const float* b_hh0 = (const float*)d_in[4];
    const float* w_ih1 = (const float*)d_in[5];
    const float* w_hh1 = (const float*)d_in[6];
    const float* b_ih1 = (const float*)d_in[7];
    const float* b_hh1 = (const float*)d_in[8];
    const float* w_out = (const float*)d_in[9];
    const float* b_out = (const float*)d_in[10];
    float* out = (float*)d_out;

    ushort* xg  = (ushort*)d_ws;                                   // 128 MiB
    ushort* h1g = (ushort*)((char*)d_ws + (size_t)BT * 256 * 2);   //  32 MiB

    hipLaunchKernelGGL(xg_mfma, dim3(BT / 64), dim3(256), 0, stream, x, w_ih0, xg);
    hipLaunchKernelGGL(lstm2_core, dim3(BB), dim3(192), 0, stream,
                       w_hh0, b_ih0, b_hh0, w_ih1, w_hh1, b_ih1, b_hh1, xg, h1g);
    hipLaunchKernelGGL(head_gemv, dim3(BT / 256), dim3(256), 0, stream,
                       h1g, w_out, b_out, out);
}

// Round 2
// 811.277 us; speedup vs baseline: 1.0332x; 1.0332x over previous
//
#include <hip/hip_runtime.h>

#define BB 256
#define TT 1024
#define II 128
#define HH 64
#define BT (BB * TT)

typedef _Float16 h2 __attribute__((ext_vector_type(2)));
typedef _Float16 half8 __attribute__((ext_vector_type(8)));
typedef float f32x4 __attribute__((ext_vector_type(4)));
typedef unsigned int uint;
typedef unsigned short ushort;

#define DOT2(a, b, c) __builtin_amdgcn_fdot2((a), (b), (c), false)
#define BC(u) __builtin_bit_cast(h2, (uint)(u))
#define MFMA16(a, b, c) __builtin_amdgcn_mfma_f32_16x16x32_f16((a), (b), (c), 0, 0, 0)
#define SIG(v) __builtin_amdgcn_rcpf(1.0f + __expf(-(v)))
#define TNH(v) (1.0f - 2.0f * __builtin_amdgcn_rcpf(1.0f + __expf(2.0f * (v))))

// R11: one barrier per 2 steps. Full lgkm drain (R9-proven semantics) — the
// counted-tail variants (R10) were neutral-to-negative; robustness wins.
#define BAR() asm volatile("s_waitcnt lgkmcnt(0)\n\ts_barrier" ::: "memory")

#define LDPK(P, ptr) uint P; { float2 _f = *(const float2*)(ptr); \
    h2 _h; _h[0] = (_Float16)_f.x; _h[1] = (_Float16)_f.y; \
    P = __builtin_bit_cast(uint, _h); }
#define PIN8(a,b,c,d,e,f,g,h_) asm volatile("" : "+v"(a),"+v"(b),"+v"(c),"+v"(d),"+v"(e),"+v"(f),"+v"(g),"+v"(h_));
#define LD8(P, base, o) \
    LDPK(P##0,(base)+(o)+ 0) LDPK(P##1,(base)+(o)+ 2) LDPK(P##2,(base)+(o)+ 4) LDPK(P##3,(base)+(o)+ 6) \
    LDPK(P##4,(base)+(o)+ 8) LDPK(P##5,(base)+(o)+10) LDPK(P##6,(base)+(o)+12) LDPK(P##7,(base)+(o)+14) \
    PIN8(P##0,P##1,P##2,P##3,P##4,P##5,P##6,P##7)

#define D8A(P, va, vb, c0, c1, c2, c3) \
    c0 = DOT2(BC(P##0), BC((va).x), c0); c1 = DOT2(BC(P##1), BC((va).y), c1); \
    c2 = DOT2(BC(P##2), BC((va).z), c2); c3 = DOT2(BC(P##3), BC((va).w), c3); \
    c0 = DOT2(BC(P##4), BC((vb).x), c0); c1 = DOT2(BC(P##5), BC((vb).y), c1); \
    c2 = DOT2(BC(P##6), BC((vb).z), c2); c3 = DOT2(BC(P##7), BC((vb).w), c3);

#define GDOT(G, s) { float a0=0.f,a1=0.f,a2=0.f,a3=0.f; \
    D8A(G##A, hv0, hv1, a0,a1,a2,a3) D8A(G##B, hv2, hv3, a0,a1,a2,a3) \
    D8A(G##C, hv4, hv5, a0,a1,a2,a3) D8A(G##D, hv6, hv7, a0,a1,a2,a3) \
    s = (a0 + a1) + (a2 + a3); }

// load full h-vector (64 f16 = 8 x b128 broadcast) into hv0..hv7 registers
#define LDHV(src) { const uint4* hq_ = (const uint4*)(src); \
    hv0=hq_[0]; hv1=hq_[1]; hv2=hq_[2]; hv3=hq_[3]; \
    hv4=hq_[4]; hv5=hq_[5]; hv6=hq_[6]; hv7=hq_[7]; }

// ============ Kernel A: xg2[b][j][t][g] = x[b,t,:] . w_ih0[g*64+j,:]  (f16) ==
// R11 layout change: t is the innermost-but-one dim so the core's P-wave can
// load ONE dwordx4 = 2 steps of gates (contiguous 8 ushorts per (b,j)).
// W-rows stay permuted at LDS-staging (srcrow = g*64+j for col 4j+g).
__global__ __launch_bounds__(256)
void xg_mfma(const float* __restrict__ x, const float* __restrict__ w_ih0,
             ushort* __restrict__ xg)
{
    __shared__ __align__(16) _Float16 xt[64][136];
    __shared__ __align__(16) _Float16 wt[128][136];
    const int tid = threadIdx.x, lane = tid & 63, wv = tid >> 6;
    const int bt0 = blockIdx.x * 64;
    {
        const int row = tid >> 2, q = (tid & 3) * 32;
        const float4* src = (const float4*)(x + (size_t)(bt0 + row) * II + q);
        _Float16* dst = &xt[row][q];
        #pragma unroll
        for (int i = 0; i < 8; ++i) {
            float4 v = src[i];
            dst[4*i+0]=(_Float16)v.x; dst[4*i+1]=(_Float16)v.y;
            dst[4*i+2]=(_Float16)v.z; dst[4*i+3]=(_Float16)v.w;
        }
    }
    for (int nh = 0; nh < 2; ++nh) {
        __syncthreads();
        {
            const int n = tid >> 1, kh = (tid & 1) * 64;
            const int flatn = nh * 128 + n;
            const int srcrow = (flatn & 3) * 64 + (flatn >> 2);   // gate-row permute
            const float4* src = (const float4*)(w_ih0 + (size_t)srcrow * II + kh);
            _Float16* dst = &wt[n][kh];
            #pragma unroll
            for (int i = 0; i < 16; ++i) {
                float4 v = src[i];
                dst[4*i+0]=(_Float16)v.x; dst[4*i+1]=(_Float16)v.y;
                dst[4*i+2]=(_Float16)v.z; dst[4*i+3]=(_Float16)v.w;
            }
        }
        __syncthreads();
        const int m = wv * 16 + (lane & 15);
        const int kf = (lane >> 4) * 8;
        half8 a0 = *(const half8*)&xt[m][ 0 + kf];
        half8 a1 = *(const half8*)&xt[m][32 + kf];
        half8 a2 = *(const half8*)&xt[m][64 + kf];
        half8 a3 = *(const half8*)&xt[m][96 + kf];
        #pragma unroll
        for (int nt = 0; nt < 8; ++nt) {
            const int nloc = nt * 16 + (lane & 15);
            half8 b0 = *(const half8*)&wt[nloc][ 0 + kf];
            half8 b1 = *(const half8*)&wt[nloc][32 + kf];
            half8 b2 = *(const half8*)&wt[nloc][64 + kf];
            half8 b3 = *(const half8*)&wt[nloc][96 + kf];
            f32x4 acc = {0.f, 0.f, 0.f, 0.f};
            acc = MFMA16(a0, b0, acc); acc = MFMA16(a1, b1, acc);
            acc = MFMA16(a2, b2, acc); acc = MFMA16(a3, b3, acc);
            const int colg = nh * 128 + nt * 16 + (lane & 15);  // == 4j+g slot
            const int jj = colg >> 2, gg = colg & 3;
            const int r0 = wv * 16 + (lane >> 4) * 4;
            const int bloc = bt0 >> 10;            // 64 | 1024 => b const/block
            const int tb = (bt0 & 1023) + r0;
            ushort* dst = xg + ((size_t)(bloc * 64 + jj) << 12) + gg;
            #pragma unroll
            for (int r = 0; r < 4; ++r) {
                _Float16 hv = (_Float16)acc[r];
                dst[(size_t)(tb + r) * 4] = __builtin_bit_cast(ushort, hv);
            }
        }
    }
}

// ============ Kernel B: 3-wave pipelined recurrence, 1 block per batch elem ==
// Wave 0 (P):  h0(k)   = lstm0(xg(k), h0(k-1))            [W_hh0 in-lane]
// Wave 1 (Q1): z(k-3)  = W_ih1 . h0(k-3)                  [W_ih1 in-lane]
// Wave 2 (Q2): h1(k-6) = act(z(k-6) + W_hh1.h1(k-7) + b)  [W_hh1 in-lane]
// R11: barrier every 2 steps (half the syncs); lags widened so every
// cross-wave register read is >=1 barrier after its producing write
// (windows {2n,2n+1}: h0 written@i read@i+2; z written@m+3 read@m+5).
// P's xg loads: one dwordx4 per pair from the [b][j][t][g] layout, rolling
// 3-reg buffer at distance 4 steps -> at most one outstanding global load
// per barrier instead of one per step.
__global__ __launch_bounds__(192) __attribute__((amdgpu_waves_per_eu(1, 1)))
void lstm2_core(const float* __restrict__ w_hh0,
                const float* __restrict__ b_ih0, const float* __restrict__ b_hh0,
                const float* __restrict__ w_ih1, const float* __restrict__ w_hh1,
                const float* __restrict__ b_ih1, const float* __restrict__ b_hh1,
                const ushort* __restrict__ xg, ushort* __restrict__ h1g)
{
    const int bb = blockIdx.x;
    const int w  = threadIdx.x >> 6;
    const int j  = threadIdx.x & 63;

    __shared__ __align__(16) uint  h0buf[8][32];     // 8-deep, 64 f16 each
    __shared__ __align__(16) uint  h1buf[32];        // Q2-private
    __shared__ __align__(16) float zbuf[8][64][4];   // 8-deep float4/lane

    // ---- weights: all three waves load a [256][64] matrix, 4 rows/lane ----
    const float* Wsel = (w == 0) ? w_hh0 : (w == 1) ? w_ih1 : w_hh1;
    const float* r0p = Wsel + (size_t)(  0 + j) * 64;
    const float* r1p = Wsel + (size_t)( 64 + j) * 64;
    const float* r2p = Wsel + (size_t)(128 + j) * 64;
    const float* r3p = Wsel + (size_t)(192 + j) * 64;
    LD8(G0A, r0p,  0) LD8(G0B, r0p, 16) LD8(G0C, r0p, 32) LD8(G0D, r0p, 48)
    LD8(G1A, r1p,  0) LD8(G1B, r1p, 16) LD8(G1C, r1p, 32) LD8(G1D, r1p, 48)
    LD8(G2A, r2p,  0) LD8(G2B, r2p, 16) LD8(G2C, r2p, 32) LD8(G2D, r2p, 48)
    LD8(G3A, r3p,  0) LD8(G3B, r3p, 16) LD8(G3C, r3p, 32) LD8(G3D, r3p, 48)

    float bI = 0.f, bF = 0.f, bG = 0.f, bO = 0.f;
    if (w == 0) {
        bI = b_ih0[j]       + b_hh0[j];
        bF = b_ih0[64 + j]  + b_hh0[64 + j];
        bG = b_ih0[128 + j] + b_hh0[128 + j];
        bO = b_ih0[192 + j] + b_hh0[192 + j];
    } else if (w == 2) {
        bI = b_ih1[j]       + b_hh1[j];
        bF = b_ih1[64 + j]  + b_hh1[64 + j];
        bG = b_ih1[128 + j] + b_hh1[128 + j];
        bO = b_ih1[192 + j] + b_hh1[192 + j];
    }

    float cst = 0.0f;
    const ushort* xb = xg + ((size_t)(bb * 64 + j) << 12);   // [b][j][t][g]
    ushort* h1b = h1g + (size_t)bb * TT * 64 + j;

    // loop-carried register state (zero == step -1 h-states)
    uint4 hv0={0,0,0,0}, hv1={0,0,0,0}, hv2={0,0,0,0}, hv3={0,0,0,0};
    uint4 hv4={0,0,0,0}, hv5={0,0,0,0}, hv6={0,0,0,0}, hv7={0,0,0,0};
    f32x4 zr = {0.f, 0.f, 0.f, 0.f};
    uint4 q0 = {0,0,0,0}, q1 = {0,0,0,0};
    if (w == 0) {
        q0 = *(const uint4*)(xb);          // pair 0: steps 0,1
        q1 = *(const uint4*)(xb + 8);      // pair 1: steps 2,3
    }

#define PSTEP(KK, XLO, XHI) \
    if ((KK) < TT) { \
        float si, sf, sg, so; \
        GDOT(G0, si) GDOT(G1, sf) GDOT(G2, sg) GDOT(G3, so) \
        h2 xlo = BC(XLO), xhi = BC(XHI); \
        si += bI + (float)xlo[0]; sf += bF + (float)xlo[1]; \
        sg += bG + (float)xhi[0]; so += bO + (float)xhi[1]; \
        float ii = SIG(si), ff = SIG(sf), gg = TNH(sg), oo = SIG(so); \
        cst = fmaf(ff, cst, ii * gg); \
        float hval = oo * TNH(cst); \
        ((_Float16*)&h0buf[(KK) & 7][0])[j] = (_Float16)hval; \
        LDHV(&h0buf[(KK) & 7][0]); \
    }

#define Q1STEP(KK) { const int i_ = (KK); \
    if (i_ >= 3 && i_ < TT + 3) { \
        const int m_ = i_ - 3; \
        float si, sf, sg, so; \
        GDOT(G0, si) GDOT(G1, sf) GDOT(G2, sg) GDOT(G3, so) \
        f32x4 zv = {si, sf, sg, so}; \
        *(f32x4*)&zbuf[m_ & 7][j][0] = zv; \
    } \
    if (i_ >= 2 && i_ < TT + 2) LDHV(&h0buf[(i_ - 2) & 7][0]) }

#define Q2STEP(KK) { const int i_ = (KK); \
    if (i_ >= 6) { \
        const int m_ = i_ - 6; \
        float si, sf, sg, so; \
        GDOT(G0, si) GDOT(G1, sf) GDOT(G2, sg) GDOT(G3, so) \
        si += bI + zr[0]; sf += bF + zr[1]; \
        sg += bG + zr[2]; so += bO + zr[3]; \
        float ii = SIG(si), ff = SIG(sf), gg = TNH(sg), oo = SIG(so); \
        cst = fmaf(ff, cst, ii * gg); \
        float hval = oo * TNH(cst); \
        _Float16 hf = (_Float16)hval; \
        ((_Float16*)&h1buf[0])[j] = hf; \
        LDHV(&h1buf[0]); \
        h1b[(size_t)m_ * 64] = __builtin_bit_cast(ushort, hf); \
    } \
    if (i_ >= 5 && i_ < TT + 5) zr = *(const f32x4*)&zbuf[(i_ - 5) & 7][j][0]; }

    for (int k0 = 0; k0 < TT + 6; k0 += 2) {
        if (w == 0) {
            uint4 qn = q1;
            if (k0 + 4 < TT)                      // pair k0/2+2: steps k0+4,k0+5
                qn = *(const uint4*)(xb + (size_t)(k0 + 4) * 4);
            PSTEP(k0,     q0.x, q0.y)
            PSTEP(k0 + 1, q0.z, q0.w)
            q0 = q1; q1 = qn;
        } else if (w == 1) {
            Q1STEP(k0)
            Q1STEP(k0 + 1)
        } else {
            Q2STEP(k0)
            Q2STEP(k0 + 1)
        }
        BAR();
    }
#undef PSTEP
#undef Q1STEP
#undef Q2STEP
}

// ============ Kernel C: out[bt] = sigmoid(h1g[bt,:] . w_out + b_out) =========
__global__ __launch_bounds__(256)
void head_gemv(const ushort* __restrict__ h1g, const float* __restrict__ w_out,
               const float* __restrict__ b_out, float* __restrict__ outp)
{
    __shared__ float wsh[64];
    const int tid = threadIdx.x;
    if (tid < 64) wsh[tid] = w_out[tid];
    __syncthreads();
    const int bt = blockIdx.x * 256 + tid;
    const uint4* hp = (const uint4*)(h1g + (size_t)bt * 64);
    float s = 0.0f;
    #pragma unroll
    for (int i = 0; i < 8; ++i) {
        uint4 v = hp[i];
        const float* wp = &wsh[8 * i];
        h2 p;
        p = BC(v.x); s = fmaf((float)p[0], wp[0], s); s = fmaf((float)p[1], wp[1], s);
        p = BC(v.y); s = fmaf((float)p[0], wp[2], s); s = fmaf((float)p[1], wp[3], s);
        p = BC(v.z); s = fmaf((float)p[0], wp[4], s); s = fmaf((float)p[1], wp[5], s);
        p = BC(v.w); s = fmaf((float)p[0], wp[6], s); s = fmaf((float)p[1], wp[7], s);
    }
    outp[bt] = __builtin_amdgcn_rcpf(1.0f + __expf(-(s + b_out[0])));
}

extern "C" void kernel_launch(void* const* d_in, const int* in_sizes, int n_in,
                              void* d_out, int out_size, void* d_ws, size_t ws_size,
                              hipStream_t stream) {
    const float* x     = (const float*)d_in[0];
    const float* w_ih0 = (const float*)d_in[1];
    const float* w_hh0 = (const float*)d_in[2];
    const float* b_ih0 = (const float*)d_in[3];
    const float* b_hh0 = (const float*)d_in[4];
    const float* w_ih1 = (const float*)d_in[5];
    const float* w_hh1 = (const float*)d_in[6];
    const float* b_ih1 = (const float*)d_in[7];
    const float* b_hh1 = (const float*)d_in[8];
    const float* w_out = (const float*)d_in[9];
    const float* b_out = (const float*)d_in[10];
    float* out = (float*)d_out;

    ushort* xg  = (ushort*)d_ws;                                   // 128 MiB
    ushort* h1g = (ushort*)((char*)d_ws + (size_t)BT * 256 * 2);   //  32 MiB

    hipLaunchKernelGGL(xg_mfma, dim3(BT / 64), dim3(256), 0, stream, x, w_ih0, xg);
    hipLaunchKernelGGL(lstm2_core, dim3(BB), dim3(192), 0, stream,
                       w_hh0, b_ih0, b_hh0, w_ih1, w_hh1, b_ih1, b_hh1, xg, h1g);
    hipLaunchKernelGGL(head_gemv, dim3(BT / 256), dim3(256), 0, stream,
                       h1g, w_out, b_out, out);
}

// Round 3
// 758.328 us; speedup vs baseline: 1.1054x; 1.0698x over previous
//
#include <hip/hip_runtime.h>

#define BB 256
#define TT 1024
#define II 128
#define HH 64
#define BT (BB * TT)

typedef _Float16 h2 __attribute__((ext_vector_type(2)));
typedef _Float16 half8 __attribute__((ext_vector_type(8)));
typedef float f32x4 __attribute__((ext_vector_type(4)));
typedef unsigned int uint;
typedef unsigned short ushort;

#define BC(u) __builtin_bit_cast(h2, (uint)(u))
#define MFMA16(a, b, c) __builtin_amdgcn_mfma_f32_16x16x32_f16((a), (b), (c), 0, 0, 0)
#define SIG(v) __builtin_amdgcn_rcpf(1.0f + __expf(-(v)))
#define TNH(v) (1.0f - 2.0f * __builtin_amdgcn_rcpf(1.0f + __expf(2.0f * (v))))

// one barrier per 2 steps, full lgkm drain (R11-verified schedule)
#define BAR() asm volatile("s_waitcnt lgkmcnt(0)\n\ts_barrier" ::: "memory")

__device__ __forceinline__ uint pk2(float a, float b) {
    h2 h; h[0] = (_Float16)a; h[1] = (_Float16)b;
    return __builtin_bit_cast(uint, h);
}

// ============ Kernel A: xg[b][j][t][g] = x[b,t,:] . w_ih0[g*64+j,:]  (f16) ==
// (unchanged from R11: [b][j][t][g] layout, W-row permute at LDS staging)
__global__ __launch_bounds__(256)
void xg_mfma(const float* __restrict__ x, const float* __restrict__ w_ih0,
             ushort* __restrict__ xg)
{
    __shared__ __align__(16) _Float16 xt[64][136];
    __shared__ __align__(16) _Float16 wt[128][136];
    const int tid = threadIdx.x, lane = tid & 63, wv = tid >> 6;
    const int bt0 = blockIdx.x * 64;
    {
        const int row = tid >> 2, q = (tid & 3) * 32;
        const float4* src = (const float4*)(x + (size_t)(bt0 + row) * II + q);
        _Float16* dst = &xt[row][q];
        #pragma unroll
        for (int i = 0; i < 8; ++i) {
            float4 v = src[i];
            dst[4*i+0]=(_Float16)v.x; dst[4*i+1]=(_Float16)v.y;
            dst[4*i+2]=(_Float16)v.z; dst[4*i+3]=(_Float16)v.w;
        }
    }
    for (int nh = 0; nh < 2; ++nh) {
        __syncthreads();
        {
            const int n = tid >> 1, kh = (tid & 1) * 64;
            const int flatn = nh * 128 + n;
            const int srcrow = (flatn & 3) * 64 + (flatn >> 2);   // gate-row permute
            const float4* src = (const float4*)(w_ih0 + (size_t)srcrow * II + kh);
            _Float16* dst = &wt[n][kh];
            #pragma unroll
            for (int i = 0; i < 16; ++i) {
                float4 v = src[i];
                dst[4*i+0]=(_Float16)v.x; dst[4*i+1]=(_Float16)v.y;
                dst[4*i+2]=(_Float16)v.z; dst[4*i+3]=(_Float16)v.w;
            }
        }
        __syncthreads();
        const int m = wv * 16 + (lane & 15);
        const int kf = (lane >> 4) * 8;
        half8 a0 = *(const half8*)&xt[m][ 0 + kf];
        half8 a1 = *(const half8*)&xt[m][32 + kf];
        half8 a2 = *(const half8*)&xt[m][64 + kf];
        half8 a3 = *(const half8*)&xt[m][96 + kf];
        #pragma unroll
        for (int nt = 0; nt < 8; ++nt) {
            const int nloc = nt * 16 + (lane & 15);
            half8 b0 = *(const half8*)&wt[nloc][ 0 + kf];
            half8 b1 = *(const half8*)&wt[nloc][32 + kf];
            half8 b2 = *(const half8*)&wt[nloc][64 + kf];
            half8 b3 = *(const half8*)&wt[nloc][96 + kf];
            f32x4 acc = {0.f, 0.f, 0.f, 0.f};
            acc = MFMA16(a0, b0, acc); acc = MFMA16(a1, b1, acc);
            acc = MFMA16(a2, b2, acc); acc = MFMA16(a3, b3, acc);
            const int colg = nh * 128 + nt * 16 + (lane & 15);  // == 4j+g slot
            const int jj = colg >> 2, gg = colg & 3;
            const int r0 = wv * 16 + (lane >> 4) * 4;
            const int bloc = bt0 >> 10;
            const int tb = (bt0 & 1023) + r0;
            ushort* dst = xg + ((size_t)(bloc * 64 + jj) << 12) + gg;
            #pragma unroll
            for (int r = 0; r < 4; ++r) {
                _Float16 hv = (_Float16)acc[r];
                dst[(size_t)(tb + r) * 4] = __builtin_bit_cast(ushort, hv);
            }
        }
    }
}

// ============ Kernel B: 3-wave pipelined recurrence, MFMA GEMV (R12) ========
// R12: each wave's 256x64 GEMV moves from 128 v_dot2 (quarter-rate; measured
// ~1340 cy/step scheduling-invariant across R9-R11 => issue-bound) to 32
// v_mfma_f32_16x16x32_f16 on the per-SIMD matrix pipe.
//   A (16x32) = h replicated across all 16 rows: A-frag for lane l is
//     h[(l>>4)*8 .. +7] — independent of l&15 -> one ds_read_b128 per k-half.
//   B (32x16) tile t: B[k][c] = W[(t&3)*64 + (t>>2)*16 + c][k]  (per-lane rows)
//   D: col=l&15, rows identical. Gate g of unit j lives in tile (j>>4)*4+g at
//     col j&15 -> 3-cndmask select per gate, zero cross-lane traffic.
// Wave 0 (P):  h0(k)   = lstm0(xg(k), h0(k-1))            [W_hh0 frags]
// Wave 1 (Q1): z(k-3)  = W_ih1 . h0(k-3)                  [W_ih1 frags]
// Wave 2 (Q2): h1(k-6) = act(z(k-6) + W_hh1.h1(k-7) + b)  [W_hh1 frags]
// Barrier per 2 steps; lags/buffers identical to R11 (verified).
__global__ __launch_bounds__(192) __attribute__((amdgpu_waves_per_eu(1, 1)))
void lstm2_core(const float* __restrict__ w_hh0,
                const float* __restrict__ b_ih0, const float* __restrict__ b_hh0,
                const float* __restrict__ w_ih1, const float* __restrict__ w_hh1,
                const float* __restrict__ b_ih1, const float* __restrict__ b_hh1,
                const ushort* __restrict__ xg, ushort* __restrict__ h1g)
{
    const int bb = blockIdx.x;
    const int w  = threadIdx.x >> 6;
    const int j  = threadIdx.x & 63;
    const int qq = j >> 4, cc = j & 15;

    __shared__ __align__(16) uint  h0buf[8][32];     // 8-deep, 64 f16 each
    __shared__ __align__(16) uint  h1buf[32];        // Q2-private
    __shared__ __align__(16) float zbuf[8][64][4];   // 8-deep float4/lane

    // ---- weight fragments: 16 tiles x 2 k-halves, 8 f16 each ----
    const float* Wsel = (w == 0) ? w_hh0 : (w == 1) ? w_ih1 : w_hh1;
    uint4 Bf[16][2];
    #pragma unroll
    for (int t = 0; t < 16; ++t) {
        const int row = (t & 3) * 64 + (t >> 2) * 16 + cc;
        const float* rp = Wsel + (size_t)row * 64 + qq * 8;
        #pragma unroll
        for (int kh = 0; kh < 2; ++kh) {
            const float* p = rp + kh * 32;
            uint4 v;
            v.x = pk2(p[0], p[1]); v.y = pk2(p[2], p[3]);
            v.z = pk2(p[4], p[5]); v.w = pk2(p[6], p[7]);
            Bf[t][kh] = v;
        }
    }

    float bI = 0.f, bF = 0.f, bG = 0.f, bO = 0.f;
    if (w == 0) {
        bI = b_ih0[j]       + b_hh0[j];
        bF = b_ih0[64 + j]  + b_hh0[64 + j];
        bG = b_ih0[128 + j] + b_hh0[128 + j];
        bO = b_ih0[192 + j] + b_hh0[192 + j];
    } else if (w == 2) {
        bI = b_ih1[j]       + b_hh1[j];
        bF = b_ih1[64 + j]  + b_hh1[64 + j];
        bG = b_ih1[128 + j] + b_hh1[128 + j];
        bO = b_ih1[192 + j] + b_hh1[192 + j];
    }

    float cst = 0.0f;
    const ushort* xb = xg + ((size_t)(bb * 64 + j) << 12);   // [b][j][t][g]
    ushort* h1b = h1g + (size_t)bb * TT * 64 + j;

    const f32x4 ZR4 = {0.f, 0.f, 0.f, 0.f};
    const int qlo = qq & 1, qhi = qq >> 1;

    // loop-carried register state (zero == step -1 h-states)
    half8 af0 = {0,0,0,0,0,0,0,0}, af1 = {0,0,0,0,0,0,0,0};
    f32x4 zr = {0.f, 0.f, 0.f, 0.f};
    uint4 q0 = {0,0,0,0}, q1 = {0,0,0,0};
    if (w == 0) {
        q0 = *(const uint4*)(xb);          // pair 0: steps 0,1
        q1 = *(const uint4*)(xb + 8);      // pair 1: steps 2,3
    }

// A-frags for next step from an h-vector (64 f16) in LDS: per-lane 16B reads
// at byte offsets qq*16 (k=0..31) and 64+qq*16 (k=32..63). Broadcast within
// each 16-lane group; 4 distinct addresses hit disjoint banks.
#define LDAF(SRC) { const char* hb_ = (const char*)(SRC); \
    af0 = *(const half8*)(hb_ + (qq << 4)); \
    af1 = *(const half8*)(hb_ + 64 + (qq << 4)); }

// MFMA GEMV + gate extraction (rows of D identical; element 0 suffices)
#define GEMV16(SI, SF, SG, SO) { \
    f32x4 D[16]; \
    _Pragma("unroll") \
    for (int t = 0; t < 16; ++t) { \
        f32x4 d_ = MFMA16(af0, __builtin_bit_cast(half8, Bf[t][0]), ZR4); \
        D[t] = MFMA16(af1, __builtin_bit_cast(half8, Bf[t][1]), d_); } \
    { float a_, b_; \
      a_ = qlo ? D[ 4][0] : D[ 0][0]; b_ = qlo ? D[12][0] : D[ 8][0]; SI = qhi ? b_ : a_; \
      a_ = qlo ? D[ 5][0] : D[ 1][0]; b_ = qlo ? D[13][0] : D[ 9][0]; SF = qhi ? b_ : a_; \
      a_ = qlo ? D[ 6][0] : D[ 2][0]; b_ = qlo ? D[14][0] : D[10][0]; SG = qhi ? b_ : a_; \
      a_ = qlo ? D[ 7][0] : D[ 3][0]; b_ = qlo ? D[15][0] : D[11][0]; SO = qhi ? b_ : a_; } }

#define PSTEP(KK, XLO, XHI) \
    if ((KK) < TT) { \
        float si, sf, sg, so; \
        GEMV16(si, sf, sg, so) \
        h2 xlo = BC(XLO), xhi = BC(XHI); \
        si += bI + (float)xlo[0]; sf += bF + (float)xlo[1]; \
        sg += bG + (float)xhi[0]; so += bO + (float)xhi[1]; \
        float ii = SIG(si), ff = SIG(sf), gg = TNH(sg), oo = SIG(so); \
        cst = fmaf(ff, cst, ii * gg); \
        float hval = oo * TNH(cst); \
        ((_Float16*)&h0buf[(KK) & 7][0])[j] = (_Float16)hval; \
        LDAF(&h0buf[(KK) & 7][0]) \
    }

#define Q1STEP(KK) { const int i_ = (KK); \
    if (i_ >= 3 && i_ < TT + 3) { \
        const int m_ = i_ - 3; \
        float si, sf, sg, so; \
        GEMV16(si, sf, sg, so) \
        f32x4 zv = {si, sf, sg, so}; \
        *(f32x4*)&zbuf[m_ & 7][j][0] = zv; \
    } \
    if (i_ >= 2 && i_ < TT + 2) LDAF(&h0buf[(i_ - 2) & 7][0]) }

#define Q2STEP(KK) { const int i_ = (KK); \
    if (i_ >= 6) { \
        const int m_ = i_ - 6; \
        float si, sf, sg, so; \
        GEMV16(si, sf, sg, so) \
        si += bI + zr[0]; sf += bF + zr[1]; \
        sg += bG + zr[2]; so += bO + zr[3]; \
        float ii = SIG(si), ff = SIG(sf), gg = TNH(sg), oo = SIG(so); \
        cst = fmaf(ff, cst, ii * gg); \
        float hval = oo * TNH(cst); \
        _Float16 hf = (_Float16)hval; \
        ((_Float16*)&h1buf[0])[j] = hf; \
        LDAF(&h1buf[0]) \
        h1b[(size_t)m_ * 64] = __builtin_bit_cast(ushort, hf); \
    } \
    if (i_ >= 5 && i_ < TT + 5) zr = *(const f32x4*)&zbuf[(i_ - 5) & 7][j][0]; }

    for (int k0 = 0; k0 < TT + 6; k0 += 2) {
        if (w == 0) {
            uint4 qn = q1;
            if (k0 + 4 < TT)
                qn = *(const uint4*)(xb + (size_t)(k0 + 4) * 4);
            PSTEP(k0,     q0.x, q0.y)
            PSTEP(k0 + 1, q0.z, q0.w)
            q0 = q1; q1 = qn;
        } else if (w == 1) {
            Q1STEP(k0)
            Q1STEP(k0 + 1)
        } else {
            Q2STEP(k0)
            Q2STEP(k0 + 1)
        }
        BAR();
    }
#undef PSTEP
#undef Q1STEP
#undef Q2STEP
#undef GEMV16
#undef LDAF
}

// ============ Kernel C: out[bt] = sigmoid(h1g[bt,:] . w_out + b_out) =========
__global__ __launch_bounds__(256)
void head_gemv(const ushort* __restrict__ h1g, const float* __restrict__ w_out,
               const float* __restrict__ b_out, float* __restrict__ outp)
{
    __shared__ float wsh[64];
    const int tid = threadIdx.x;
    if (tid < 64) wsh[tid] = w_out[tid];
    __syncthreads();
    const int bt = blockIdx.x * 256 + tid;
    const uint4* hp = (const uint4*)(h1g + (size_t)bt * 64);
    float s = 0.0f;
    #pragma unroll
    for (int i = 0; i < 8; ++i) {
        uint4 v = hp[i];
        const float* wp = &wsh[8 * i];
        h2 p;
        p = BC(v.x); s = fmaf((float)p[0], wp[0], s); s = fmaf((float)p[1], wp[1], s);
        p = BC(v.y); s = fmaf((float)p[0], wp[2], s); s = fmaf((float)p[1], wp[3], s);
        p = BC(v.z); s = fmaf((float)p[0], wp[4], s); s = fmaf((float)p[1], wp[5], s);
        p = BC(v.w); s = fmaf((float)p[0], wp[6], s); s = fmaf((float)p[1], wp[7], s);
    }
    outp[bt] = __builtin_amdgcn_rcpf(1.0f + __expf(-(s + b_out[0])));
}

extern "C" void kernel_launch(void* const* d_in, const int* in_sizes, int n_in,
                              void* d_out, int out_size, void* d_ws, size_t ws_size,
                              hipStream_t stream) {
    const float* x     = (const float*)d_in[0];
    const float* w_ih0 = (const float*)d_in[1];
    const float* w_hh0 = (const float*)d_in[2];
    const float* b_ih0 = (const float*)d_in[3];
    const float* b_hh0 = (const float*)d_in[4];
    const float* w_ih1 = (const float*)d_in[5];
    const float* w_hh1 = (const float*)d_in[6];
    const float* b_ih1 = (const float*)d_in[7];
    const float* b_hh1 = (const float*)d_in[8];
    const float* w_out = (const float*)d_in[9];
    const float* b_out = (const float*)d_in[10];
    float* out = (float*)d_out;

    ushort* xg  = (ushort*)d_ws;                                   // 128 MiB
    ushort* h1g = (ushort*)((char*)d_ws + (size_t)BT * 256 * 2);   //  32 MiB

    hipLaunchKernelGGL(xg_mfma, dim3(BT / 64), dim3(256), 0, stream, x, w_ih0, xg);
    hipLaunchKernelGGL(lstm2_core, dim3(BB), dim3(192), 0, stream,
                       w_hh0, b_ih0, b_hh0, w_ih1, w_hh1, b_ih1, b_hh1, xg, h1g);
    hipLaunchKernelGGL(head_gemv, dim3(BT / 256), dim3(256), 0, stream,
                       h1g, w_out, b_out, out);
}

// Round 4
// 754.383 us; speedup vs baseline: 1.1111x; 1.0052x over previous
//
#include <hip/hip_runtime.h>

#define BB 256
#define TT 1024
#define II 128
#define HH 64
#define BT (BB * TT)

typedef _Float16 h2 __attribute__((ext_vector_type(2)));
typedef _Float16 half8 __attribute__((ext_vector_type(8)));
typedef float f32x4 __attribute__((ext_vector_type(4)));
typedef unsigned int uint;
typedef unsigned short ushort;

#define BC(u) __builtin_bit_cast(h2, (uint)(u))
#define MFMA16(a, b, c) __builtin_amdgcn_mfma_f32_16x16x32_f16((a), (b), (c), 0, 0, 0)
#define SIG(v) __builtin_amdgcn_rcpf(1.0f + __expf(-(v)))
#define TNH(v) (1.0f - 2.0f * __builtin_amdgcn_rcpf(1.0f + __expf(2.0f * (v))))

// one barrier per 2 steps, full lgkm drain (R11-verified schedule)
#define BAR() asm volatile("s_waitcnt lgkmcnt(0)\n\ts_barrier" ::: "memory")

__device__ __forceinline__ uint pk2(float a, float b) {
    h2 h; h[0] = (_Float16)a; h[1] = (_Float16)b;
    return __builtin_bit_cast(uint, h);
}

// ============ Kernel A: xg[b][j][t][g] = x[b,t,:] . w_ih0[g*64+j,:]  (f16) ==
// R13: epilogue routed through an LDS staging tile. The direct D-fragment
// store was 8B chunks at 8KB stride (12.5% line use, ~8x write amplification,
// ~245us measured vs 41us roofline). Now: MFMA -> sg[64 t][256 colg] (pad 140
// kills the 8-row bank period: 70 words/row, 8 rows = 560 = 16 mod 32), then
// a write-out phase emits 512B contiguous runs per j (4x dwordx4/thread).
// Consumer layout [b][j][t][g] and f16 values bit-identical to R12.
__global__ __launch_bounds__(256)
void xg_mfma(const float* __restrict__ x, const float* __restrict__ w_ih0,
             ushort* __restrict__ xg)
{
    __shared__ __align__(16) _Float16 xt[64][136];
    __shared__ __align__(16) _Float16 wt[128][136];
    __shared__ __align__(16) ushort   sg[64][140];   // [t-local][colg-local]
    const int tid = threadIdx.x, lane = tid & 63, wv = tid >> 6;
    const int bt0 = blockIdx.x * 64;
    const int b = bt0 >> 10, t0 = bt0 & 1023;
    {
        const int row = tid >> 2, q = (tid & 3) * 32;
        const float4* src = (const float4*)(x + (size_t)(bt0 + row) * II + q);
        _Float16* dst = &xt[row][q];
        #pragma unroll
        for (int i = 0; i < 8; ++i) {
            float4 v = src[i];
            dst[4*i+0]=(_Float16)v.x; dst[4*i+1]=(_Float16)v.y;
            dst[4*i+2]=(_Float16)v.z; dst[4*i+3]=(_Float16)v.w;
        }
    }
    for (int nh = 0; nh < 2; ++nh) {
        __syncthreads();
        {
            const int n = tid >> 1, kh = (tid & 1) * 64;
            const int flatn = nh * 128 + n;
            const int srcrow = (flatn & 3) * 64 + (flatn >> 2);   // gate-row permute
            const float4* src = (const float4*)(w_ih0 + (size_t)srcrow * II + kh);
            _Float16* dst = &wt[n][kh];
            #pragma unroll
            for (int i = 0; i < 16; ++i) {
                float4 v = src[i];
                dst[4*i+0]=(_Float16)v.x; dst[4*i+1]=(_Float16)v.y;
                dst[4*i+2]=(_Float16)v.z; dst[4*i+3]=(_Float16)v.w;
            }
        }
        __syncthreads();
        const int m = wv * 16 + (lane & 15);
        const int kf = (lane >> 4) * 8;
        half8 a0 = *(const half8*)&xt[m][ 0 + kf];
        half8 a1 = *(const half8*)&xt[m][32 + kf];
        half8 a2 = *(const half8*)&xt[m][64 + kf];
        half8 a3 = *(const half8*)&xt[m][96 + kf];
        #pragma unroll
        for (int nt = 0; nt < 8; ++nt) {
            const int nloc = nt * 16 + (lane & 15);
            half8 b0 = *(const half8*)&wt[nloc][ 0 + kf];
            half8 b1 = *(const half8*)&wt[nloc][32 + kf];
            half8 b2 = *(const half8*)&wt[nloc][64 + kf];
            half8 b3 = *(const half8*)&wt[nloc][96 + kf];
            f32x4 acc = {0.f, 0.f, 0.f, 0.f};
            acc = MFMA16(a0, b0, acc); acc = MFMA16(a1, b1, acc);
            acc = MFMA16(a2, b2, acc); acc = MFMA16(a3, b3, acc);
            const int cl = nt * 16 + (lane & 15);     // colg-local (0..127)
            const int r0 = wv * 16 + (lane >> 4) * 4; // t-local
            #pragma unroll
            for (int r = 0; r < 4; ++r) {
                _Float16 hv = (_Float16)acc[r];
                sg[r0 + r][cl] = __builtin_bit_cast(ushort, hv);
            }
        }
        __syncthreads();
        // write-out: j = nh*32 + jl; 512B contiguous per j, 8 threads each.
        {
            const int jl = tid >> 3, part = tid & 7;
            const int j = nh * 32 + jl;
            ushort* gdst = xg + (((size_t)b * 64 + j) << 12)
                              + (size_t)(t0 + part * 8) * 4;
            #pragma unroll
            for (int i = 0; i < 4; ++i) {
                uint2 lo = *(const uint2*)&sg[part * 8 + 2*i    ][jl * 4];
                uint2 hi = *(const uint2*)&sg[part * 8 + 2*i + 1][jl * 4];
                uint4 v; v.x = lo.x; v.y = lo.y; v.z = hi.x; v.w = hi.y;
                *(uint4*)(gdst + i * 8) = v;
            }
        }
    }
}

// ============ Kernel B: 3-wave pipelined recurrence, MFMA GEMV (R12) ========
// (unchanged from R12 — verified at 503us; MFMA single-wave issue is its
//  bottleneck, to be attacked separately)
__global__ __launch_bounds__(192) __attribute__((amdgpu_waves_per_eu(1, 1)))
void lstm2_core(const float* __restrict__ w_hh0,
                const float* __restrict__ b_ih0, const float* __restrict__ b_hh0,
                const float* __restrict__ w_ih1, const float* __restrict__ w_hh1,
                const float* __restrict__ b_ih1, const float* __restrict__ b_hh1,
                const ushort* __restrict__ xg, ushort* __restrict__ h1g)
{
    const int bb = blockIdx.x;
    const int w  = threadIdx.x >> 6;
    const int j  = threadIdx.x & 63;
    const int qq = j >> 4, cc = j & 15;

    __shared__ __align__(16) uint  h0buf[8][32];     // 8-deep, 64 f16 each
    __shared__ __align__(16) uint  h1buf[32];        // Q2-private
    __shared__ __align__(16) float zbuf[8][64][4];   // 8-deep float4/lane

    const float* Wsel = (w == 0) ? w_hh0 : (w == 1) ? w_ih1 : w_hh1;
    uint4 Bf[16][2];
    #pragma unroll
    for (int t = 0; t < 16; ++t) {
        const int row = (t & 3) * 64 + (t >> 2) * 16 + cc;
        const float* rp = Wsel + (size_t)row * 64 + qq * 8;
        #pragma unroll
        for (int kh = 0; kh < 2; ++kh) {
            const float* p = rp + kh * 32;
            uint4 v;
            v.x = pk2(p[0], p[1]); v.y = pk2(p[2], p[3]);
            v.z = pk2(p[4], p[5]); v.w = pk2(p[6], p[7]);
            Bf[t][kh] = v;
        }
    }

    float bI = 0.f, bF = 0.f, bG = 0.f, bO = 0.f;
    if (w == 0) {
        bI = b_ih0[j]       + b_hh0[j];
        bF = b_ih0[64 + j]  + b_hh0[64 + j];
        bG = b_ih0[128 + j] + b_hh0[128 + j];
        bO = b_ih0[192 + j] + b_hh0[192 + j];
    } else if (w == 2) {
        bI = b_ih1[j]       + b_hh1[j];
        bF = b_ih1[64 + j]  + b_hh1[64 + j];
        bG = b_ih1[128 + j] + b_hh1[128 + j];
        bO = b_ih1[192 + j] + b_hh1[192 + j];
    }

    float cst = 0.0f;
    const ushort* xb = xg + ((size_t)(bb * 64 + j) << 12);   // [b][j][t][g]
    ushort* h1b = h1g + (size_t)bb * TT * 64 + j;

    const f32x4 ZR4 = {0.f, 0.f, 0.f, 0.f};
    const int qlo = qq & 1, qhi = qq >> 1;

    half8 af0 = {0,0,0,0,0,0,0,0}, af1 = {0,0,0,0,0,0,0,0};
    f32x4 zr = {0.f, 0.f, 0.f, 0.f};
    uint4 q0 = {0,0,0,0}, q1 = {0,0,0,0};
    if (w == 0) {
        q0 = *(const uint4*)(xb);          // pair 0: steps 0,1
        q1 = *(const uint4*)(xb + 8);      // pair 1: steps 2,3
    }

#define LDAF(SRC) { const char* hb_ = (const char*)(SRC); \
    af0 = *(const half8*)(hb_ + (qq << 4)); \
    af1 = *(const half8*)(hb_ + 64 + (qq << 4)); }

#define GEMV16(SI, SF, SG, SO) { \
    f32x4 D[16]; \
    _Pragma("unroll") \
    for (int t = 0; t < 16; ++t) { \
        f32x4 d_ = MFMA16(af0, __builtin_bit_cast(half8, Bf[t][0]), ZR4); \
        D[t] = MFMA16(af1, __builtin_bit_cast(half8, Bf[t][1]), d_); } \
    { float a_, b_; \
      a_ = qlo ? D[ 4][0] : D[ 0][0]; b_ = qlo ? D[12][0] : D[ 8][0]; SI = qhi ? b_ : a_; \
      a_ = qlo ? D[ 5][0] : D[ 1][0]; b_ = qlo ? D[13][0] : D[ 9][0]; SF = qhi ? b_ : a_; \
      a_ = qlo ? D[ 6][0] : D[ 2][0]; b_ = qlo ? D[14][0] : D[10][0]; SG = qhi ? b_ : a_; \
      a_ = qlo ? D[ 7][0] : D[ 3][0]; b_ = qlo ? D[15][0] : D[11][0]; SO = qhi ? b_ : a_; } }

#define PSTEP(KK, XLO, XHI) \
    if ((KK) < TT) { \
        float si, sf, sg, so; \
        GEMV16(si, sf, sg, so) \
        h2 xlo = BC(XLO), xhi = BC(XHI); \
        si += bI + (float)xlo[0]; sf += bF + (float)xlo[1]; \
        sg += bG + (float)xhi[0]; so += bO + (float)xhi[1]; \
        float ii = SIG(si), ff = SIG(sf), gg = TNH(sg), oo = SIG(so); \
        cst = fmaf(ff, cst, ii * gg); \
        float hval = oo * TNH(cst); \
        ((_Float16*)&h0buf[(KK) & 7][0])[j] = (_Float16)hval; \
        LDAF(&h0buf[(KK) & 7][0]) \
    }

#define Q1STEP(KK) { const int i_ = (KK); \
    if (i_ >= 3 && i_ < TT + 3) { \
        const int m_ = i_ - 3; \
        float si, sf, sg, so; \
        GEMV16(si, sf, sg, so) \
        f32x4 zv = {si, sf, sg, so}; \
        *(f32x4*)&zbuf[m_ & 7][j][0] = zv; \
    } \
    if (i_ >= 2 && i_ < TT + 2) LDAF(&h0buf[(i_ - 2) & 7][0]) }

#define Q2STEP(KK) { const int i_ = (KK); \
    if (i_ >= 6) { \
        const int m_ = i_ - 6; \
        float si, sf, sg, so; \
        GEMV16(si, sf, sg, so) \
        si += bI + zr[0]; sf += bF + zr[1]; \
        sg += bG + zr[2]; so += bO + zr[3]; \
        float ii = SIG(si), ff = SIG(sf), gg = TNH(sg), oo = SIG(so); \
        cst = fmaf(ff, cst, ii * gg); \
        float hval = oo * TNH(cst); \
        _Float16 hf = (_Float16)hval; \
        ((_Float16*)&h1buf[0])[j] = hf; \
        LDAF(&h1buf[0]) \
        h1b[(size_t)m_ * 64] = __builtin_bit_cast(ushort, hf); \
    } \
    if (i_ >= 5 && i_ < TT + 5) zr = *(const f32x4*)&zbuf[(i_ - 5) & 7][j][0]; }

    for (int k0 = 0; k0 < TT + 6; k0 += 2) {
        if (w == 0) {
            uint4 qn = q1;
            if (k0 + 4 < TT)
                qn = *(const uint4*)(xb + (size_t)(k0 + 4) * 4);
            PSTEP(k0,     q0.x, q0.y)
            PSTEP(k0 + 1, q0.z, q0.w)
            q0 = q1; q1 = qn;
        } else if (w == 1) {
            Q1STEP(k0)
            Q1STEP(k0 + 1)
        } else {
            Q2STEP(k0)
            Q2STEP(k0 + 1)
        }
        BAR();
    }
#undef PSTEP
#undef Q1STEP
#undef Q2STEP
#undef GEMV16
#undef LDAF
}

// ============ Kernel C: out[bt] = sigmoid(h1g[bt,:] . w_out + b_out) =========
__global__ __launch_bounds__(256)
void head_gemv(const ushort* __restrict__ h1g, const float* __restrict__ w_out,
               const float* __restrict__ b_out, float* __restrict__ outp)
{
    __shared__ float wsh[64];
    const int tid = threadIdx.x;
    if (tid < 64) wsh[tid] = w_out[tid];
    __syncthreads();
    const int bt = blockIdx.x * 256 + tid;
    const uint4* hp = (const uint4*)(h1g + (size_t)bt * 64);
    float s = 0.0f;
    #pragma unroll
    for (int i = 0; i < 8; ++i) {
        uint4 v = hp[i];
        const float* wp = &wsh[8 * i];
        h2 p;
        p = BC(v.x); s = fmaf((float)p[0], wp[0], s); s = fmaf((float)p[1], wp[1], s);
        p = BC(v.y); s = fmaf((float)p[0], wp[2], s); s = fmaf((float)p[1], wp[3], s);
        p = BC(v.z); s = fmaf((float)p[0], wp[4], s); s = fmaf((float)p[1], wp[5], s);
        p = BC(v.w); s = fmaf((float)p[0], wp[6], s); s = fmaf((float)p[1], wp[7], s);
    }
    outp[bt] = __builtin_amdgcn_rcpf(1.0f + __expf(-(s + b_out[0])));
}

extern "C" void kernel_launch(void* const* d_in, const int* in_sizes, int n_in,
                              void* d_out, int out_size, void* d_ws, size_t ws_size,
                              hipStream_t stream) {
    const float* x     = (const float*)d_in[0];
    const float* w_ih0 = (const float*)d_in[1];
    const float* w_hh0 = (const float*)d_in[2];
    const float* b_ih0 = (const float*)d_in[3];
    const float* b_hh0 = (const float*)d_in[4];
    const float* w_ih1 = (const float*)d_in[5];
    const float* w_hh1 = (const float*)d_in[6];
    const float* b_ih1 = (const float*)d_in[7];
    const float* b_hh1 = (const float*)d_in[8];
    const float* w_out = (const float*)d_in[9];
    const float* b_out = (const float*)d_in[10];
    float* out = (float*)d_out;

    ushort* xg  = (ushort*)d_ws;                                   // 128 MiB
    ushort* h1g = (ushort*)((char*)d_ws + (size_t)BT * 256 * 2);   //  32 MiB

    hipLaunchKernelGGL(xg_mfma, dim3(BT / 64), dim3(256), 0, stream, x, w_ih0, xg);
    hipLaunchKernelGGL(lstm2_core, dim3(BB), dim3(192), 0, stream,
                       w_hh0, b_ih0, b_hh0, w_ih1, w_hh1, b_ih1, b_hh1, xg, h1g);
    hipLaunchKernelGGL(head_gemv, dim3(BT / 256), dim3(256), 0, stream,
                       h1g, w_out, b_out, out);
}